// Round 10
// baseline (1454.537 us; speedup 1.0000x reference)
//
#include <hip/hip_runtime.h>
#include <math.h>

constexpr int WID  = 320;
constexpr int HWc  = 320 * 320;        // 102400
constexpr int NIMG = 16;
constexpr int NSL  = 32;               // B*C slices for TV/DWT
constexpr int NTOT = NIMG * 2 * HWc;   // 3276800 floats per full array
constexpr float LAM_TV  = 0.005f;
constexpr float LAM_WAV = 0.005f;

__device__ __forceinline__ float softt(float v) {
    float a = fmaxf(fabsf(v) - LAM_WAV, 0.f);
    return copysignf(a, v);
}

// ================= DPP cross-lane helpers (VALU, not DS pipe) ===============
// CDNA keeps gfx9 full-wave DPP (removed on RDNA): wave_shr:1 = lane i <- i-1
// (shfl_up 1), wave_shl:1 = lane i <- i+1 (shfl_down 1), quad_perm xor1/xor2.
// These issue as v_mov_b32+DPP on the VALU pipe: no DS latency (~35cyc/op) and
// no DS throughput tax (~5.8cyc/op shared per CU). R9's TV kernel did ~170 DS
// shuffles/wave -> DS-pipe-bound; DPP moves them to VALU.
// bound_ctrl=false + old=src -> invalid lanes keep own value (= HIP clamp).
template<int CTRL>
__device__ __forceinline__ float dpp_mov(float v) {
    union { float f; int i; } a, r;
    a.f = v;
    r.i = __builtin_amdgcn_update_dpp(a.i, a.i, CTRL, 0xf, 0xf, false);
    return r.f;
}
__device__ __forceinline__ float shup1(float v) { return dpp_mov<0x138>(v); } // wave_shr:1
__device__ __forceinline__ float shdn1(float v) { return dpp_mov<0x130>(v); } // wave_shl:1
__device__ __forceinline__ float xor_sh(float v, int h) {   // h compile-time after unroll
    if (h == 1) return dpp_mov<0xB1>(v);   // quad_perm [1,0,3,2]
    if (h == 2) return dpp_mov<0x4E>(v);   // quad_perm [2,3,0,1]
    return __shfl_xor(v, h);
}

// ================= 320-point FFT core ======================================
// 320 = 5 (register DFT) x 64 (lane FFT via shfl_xor). Centered transform via
// (-1)^n modulation at load and (-1)^k at store (handled by callers).
// LESSON (R3, R6): this problem is wave-supply-bound everywhere — never trade
// wave count for per-wave ILP. One line per wave, many waves.
struct Tw { float tc, ts; float stc[6], sts[6]; };

template<int SGN>
__device__ __forceinline__ Tw make_tw(int lane) {
    Tw tw;
    __sincosf((float)SGN * 6.283185307179586f * (float)lane / 320.f, &tw.ts, &tw.tc);
#pragma unroll
    for (int s = 0; s < 6; s++) {
        int h = 32 >> s;
        int j = lane & (h - 1);
        float ang = (float)SGN * 3.14159265358979323f * (float)j / (float)h;
        __sincosf(ang, &tw.sts[s], &tw.stc[s]);
    }
    return tw;
}

// vr/vi hold elements n = lane + 64m (already sign-modulated).
// out: Cr/Ci hold X[5*bitrev6(lane) + k] in slot k (unscaled).
template<int SGN>
__device__ __forceinline__ void fft320_core(const float (&vr)[5], const float (&vi)[5],
                                            float (&Cr)[5], float (&Ci)[5],
                                            const Tw& tw, int lane) {
    const float cw1 = 0.30901699437494745f, sw1 = 0.9510565162951535f;
    const float cw2 = -0.8090169943749475f, sw2 = 0.5877852522924731f;
    const float cwt[5] = {1.f, cw1, cw2, cw2, cw1};
    const float swt[5] = {0.f, sw1, sw2, -sw2, -sw1};
    Cr[0] = vr[0] + vr[1] + vr[2] + vr[3] + vr[4];
    Ci[0] = vi[0] + vi[1] + vi[2] + vi[3] + vi[4];
#pragma unroll
    for (int k = 1; k < 5; k++) {
        float ar = vr[0], ai = vi[0];
#pragma unroll
        for (int m = 1; m < 5; m++) {
            int j = (m * k) % 5;
            float wr_ = cwt[j], wi_ = (float)SGN * swt[j];
            ar += vr[m] * wr_ - vi[m] * wi_;
            ai += vr[m] * wi_ + vi[m] * wr_;
        }
        Cr[k] = ar; Ci[k] = ai;
    }
    // twiddle W_320^{lane*k}
    float twr = 1.f, twi = 0.f;
#pragma unroll
    for (int k = 1; k < 5; k++) {
        float nr = twr * tw.tc - twi * tw.ts;
        twi = twr * tw.ts + twi * tw.tc;
        twr = nr;
        float r = Cr[k] * twr - Ci[k] * twi;
        Ci[k]   = Cr[k] * twi + Ci[k] * twr;
        Cr[k]   = r;
    }
    // 6-stage radix-2 DIF across 64 lanes (h=2,1 stages via DPP quad_perm)
#pragma unroll
    for (int s = 0; s < 6; s++) {
        int h = 32 >> s;
        bool up = (lane & h) != 0;
#pragma unroll
        for (int k = 0; k < 5; k++) {
            float orr = xor_sh(Cr[k], h);
            float oii = xor_sh(Ci[k], h);
            if (up) {
                float dr = orr - Cr[k], di = oii - Ci[k];
                Cr[k] = dr * tw.stc[s] - di * tw.sts[s];
                Ci[k] = dr * tw.sts[s] + di * tw.stc[s];
            } else {
                Cr[k] += orr;
                Ci[k] += oii;
            }
        }
    }
}

// ---------------- row FFT pass (1 line/wave, 5120 waves = 5/SIMD) -----------
// EPI: 0 = plain store
//      2 = residual store: out = aux1 - val   (aux1 = z, PREFETCHED at entry:
//          k1 is known before the core, so the z loads overlap the FFT)
//      3 = dual store:     out and out2 both get val
template<int SGN, int EPI>
__global__ __launch_bounds__(256) void fft_row(const float* __restrict__ in,
                                               float* __restrict__ out,
                                               const float* __restrict__ aux1,
                                               float* __restrict__ out2) {
    const int lane = threadIdx.x & 63;
    const int wv   = threadIdx.x >> 6;
    const int L    = blockIdx.x * 4 + wv;
    const int img  = L / 320;
    const int l    = L - img * 320;
    const size_t ibase = (size_t)img * 2 * HWc;
    const float* pre = in + ibase + (size_t)l * WID;
    const float* pim = pre + HWc;
    const int k1 = (int)(__brev((unsigned)lane) >> 26);   // bitrev6

    float vr[5], vi[5];
    const float sgn_in = (lane & 1) ? -1.f : 1.f;
#pragma unroll
    for (int m = 0; m < 5; m++) {
        int n = lane + 64 * m;
        vr[m] = sgn_in * pre[n];
        vi[m] = sgn_in * pim[n];
    }
    // prefetch residual operand (z) before the latency-heavy core
    float zr[5], zi[5];
    if (EPI == 2) {
#pragma unroll
        for (int k = 0; k < 5; k++) {
            int idxs = 5 * k1 + k + l * WID;
            zr[k] = aux1[ibase + idxs];
            zi[k] = aux1[ibase + HWc + idxs];
        }
    }

    Tw tw = make_tw<SGN>(lane);
    float Cr[5], Ci[5];
    fft320_core<SGN>(vr, vi, Cr, Ci, tw, lane);

    float* qre = out + ibase + (size_t)l * WID;
    float* qim = qre + HWc;
    const float scale = 0.05590169943749474f;  // 1/sqrt(320)
#pragma unroll
    for (int k = 0; k < 5; k++) {
        int kout = 5 * k1 + k;
        float s2 = (kout & 1) ? -scale : scale;
        float re = s2 * Cr[k];
        float im = s2 * Ci[k];
        const int idxs = kout + l * WID;
        if (EPI == 2) {
            re = zr[k] - re;
            im = zi[k] - im;
        }
        qre[kout] = re;
        qim[kout] = im;
        if (EPI == 3) {
            out2[ibase + idxs]       = re;
            out2[ibase + HWc + idxs] = im;
        }
    }
}

// ---------------- fused column FFT kernel (LDS-transposed, high-TLP) --------
// Block = 512 threads (8 waves) handles 8 complex columns; ONE column line
// per wave per pass -> 640 blocks x 8 = 5120 waves (5/SIMD).
// Tile [comp][row 320][9]: stride 9, gcd(9,32)=1 -> 2-way LDS aliasing (free).
// MODE 0: single inverse column FFT (init path).
// MODE 1: forward col FFT + k-space DC (m*(m*K - y)) + inverse col FFT.
constexpr int CB   = 8;        // columns per block
constexpr int CPAD = CB + 1;   // 9

template<int SGN>
__device__ __forceinline__ void fft_line_lds(float (*tile)[320][CPAD], int cl,
                                             int lane, const Tw& tw) {
    float vr[5], vi[5], Cr[5], Ci[5];
    const float sgn_in = (lane & 1) ? -1.f : 1.f;
#pragma unroll
    for (int m = 0; m < 5; m++) {
        int n = lane + 64 * m;
        vr[m] = sgn_in * tile[0][n][cl];
        vi[m] = sgn_in * tile[1][n][cl];
    }
    fft320_core<SGN>(vr, vi, Cr, Ci, tw, lane);
    const int k1 = (int)(__brev((unsigned)lane) >> 26);
    const float scale = 0.05590169943749474f;
#pragma unroll
    for (int k = 0; k < 5; k++) {
        int kout = 5 * k1 + k;
        float s2 = (kout & 1) ? -scale : scale;
        tile[0][kout][cl] = s2 * Cr[k];
        tile[1][kout][cl] = s2 * Ci[k];
    }
}

template<int MODE>
__global__ __launch_bounds__(512) void fft_col(const float* __restrict__ in,
                                               float* __restrict__ out,
                                               const float* __restrict__ y,
                                               const float* __restrict__ mask) {
    __shared__ float tile[2][320][CPAD];   // 23 KB
    const int tid = threadIdx.x;
    const int bpi = WID / CB;              // 40 blocks per image
    const int img = blockIdx.x / bpi;
    const int c0  = (blockIdx.x - img * bpi) * CB;
    const size_t ibase = (size_t)img * 2 * HWc;
    constexpr int C4 = CB / 4;             // 2 float4 groups per row
    constexpr int NE = 320 * C4;           // 640 float4 per component

#pragma unroll
    for (int comp = 0; comp < 2; comp++) {
        const float* p = in + ibase + (size_t)comp * HWc + c0;
        for (int i = tid; i < NE; i += 512) {
            int row = i >> 1, cg = (i & 1) << 2;
            float4 v = *(const float4*)(p + row * WID + cg);
            float* t = &tile[comp][row][cg];
            t[0] = v.x; t[1] = v.y; t[2] = v.z; t[3] = v.w;
        }
    }
    __syncthreads();

    const int lane = tid & 63;
    const int wv   = tid >> 6;             // wave = column index [0,8)

    if (MODE == 1) {
        Tw twf = make_tw<-1>(lane);
        fft_line_lds<-1>(tile, wv, lane, twf);
        __syncthreads();
        // k-space data consistency, all streams coalesced
        const float* pm  = mask + (size_t)img * HWc + c0;
        const float* pyr = y + ibase + c0;
        const float* pyi = y + ibase + HWc + c0;
        for (int i = tid; i < NE; i += 512) {
            int row = i >> 1, cg = (i & 1) << 2;
            float4 m4 = *(const float4*)(pm  + row * WID + cg);
            float4 yr = *(const float4*)(pyr + row * WID + cg);
            float4 yi = *(const float4*)(pyi + row * WID + cg);
            float* tr = &tile[0][row][cg];
            float* ti = &tile[1][row][cg];
            tr[0] = m4.x * (m4.x * tr[0] - yr.x);
            tr[1] = m4.y * (m4.y * tr[1] - yr.y);
            tr[2] = m4.z * (m4.z * tr[2] - yr.z);
            tr[3] = m4.w * (m4.w * tr[3] - yr.w);
            ti[0] = m4.x * (m4.x * ti[0] - yi.x);
            ti[1] = m4.y * (m4.y * ti[1] - yi.y);
            ti[2] = m4.z * (m4.z * ti[2] - yi.z);
            ti[3] = m4.w * (m4.w * ti[3] - yi.w);
        }
        __syncthreads();
    }
    {
        Tw twi = make_tw<1>(lane);
        fft_line_lds<1>(tile, wv, lane, twi);
    }
    __syncthreads();
#pragma unroll
    for (int comp = 0; comp < 2; comp++) {
        float* p = out + ibase + (size_t)comp * HWc + c0;
        for (int i = tid; i < NE; i += 512) {
            int row = i >> 1, cg = (i & 1) << 2;
            const float* t = &tile[comp][row][cg];
            *(float4*)(p + row * WID + cg) = make_float4(t[0], t[1], t[2], t[3]);
        }
    }
}

// ============ fused TV prox + 3-level Haar shrinkage + FISTA ================
// One WAVE per tile: interior 8 rows x 48 cols (8x8-block aligned), halo 8
// cols each side (lane = col, interior lanes [8,56)), vertical halo 4 rows.
// TIR=8/halo=4 (R9): state 3x16=48 floats fits ~48 VGPR, no AGPR spill,
// 8960 waves (8.75/SIMD). R10: all +-1 shuffles via DPP (VALU) — R9 was
// DS-pipe-bound (~170 DS shuffles/wave ~ 14us of DS throughput per launch).
// Halo-4 error: boundary-p error attenuates ~(lam*tau*k) ~0.006 per ring ->
// (0.006)^4 ~ 1e-9 at interior. Rolling-u pipeline; edge/interior templated.
constexpr int HALO = 4;
constexpr int TIR = 8;                  // interior rows
constexpr int TVR = TIR + 2 * HALO;     // 16 rows per tile
constexpr int TIC = 48;                 // interior cols
constexpr int TCOLS = 7;                // ceil(320/48), last tile interior 32
constexpr int TROWS = WID / TIR;        // 40
constexpr int TPS = TROWS * TCOLS;      // 280 tiles per slice

template<bool EDGE>
__device__ __forceinline__ void tv_core(const float* __restrict__ g, int gi0, int gj,
                                        float (&uf)[TIR]) {
    float z_[TVR], px_[TVR], py_[TVR];
    const bool colin = !EDGE || ((unsigned)gj < (unsigned)WID);
#pragma unroll
    for (int r = 0; r < TVR; r++) {
        int gi = gi0 + r;
        float v = 0.f;
        if (!EDGE) {
            v = g[gi * WID + gj];
        } else {
            bool in = colin && ((unsigned)gi < (unsigned)WID);
            if (in) v = g[gi * WID + gj];
        }
        z_[r] = v; px_[r] = 0.f; py_[r] = 0.f;
    }
    const bool gj_le0 = EDGE && (gj <= 0);
    const bool gj_hi  = EDGE && (gj >= WID - 1);
    const bool gx_on  = !EDGE || (gj < WID - 1);

#pragma clang loop unroll(disable)
    for (int it = 0; it < 5; it++) {
        float ucur, unext;
        {   // u[0] (halo row; divy value don't-care for interior output)
            float pxm = shup1(px_[0]);
            float divx, divy;
            if (!EDGE) {
                divx = px_[0] - pxm;
                divy = 0.f;
            } else {
                int gi = gi0;
                divx = gj_le0 ? px_[0] : (gj_hi ? -pxm : px_[0] - pxm);
                divy = (gi <= 0) ? py_[0] : ((gi >= WID - 1) ? -py_[0] : 0.f);
            }
            ucur = z_[0] - LAM_TV * (divx + divy);
        }
#pragma unroll
        for (int r = 0; r < TVR - 1; r++) {
            {   // unext = u[r+1] from OLD p (p rows >= r not yet updated)
                float pxm = shup1(px_[r + 1]);
                float divx, divy;
                if (!EDGE) {
                    divx = px_[r + 1] - pxm;
                    divy = py_[r + 1] - py_[r];
                } else {
                    int gi1 = gi0 + r + 1;
                    divx = gj_le0 ? px_[r + 1] : (gj_hi ? -pxm : px_[r + 1] - pxm);
                    divy = (gi1 <= 0) ? py_[r + 1]
                         : ((gi1 >= WID - 1) ? -py_[r] : py_[r + 1] - py_[r]);
                }
                unext = z_[r + 1] - LAM_TV * (divx + divy);
            }
            {   // p[r] update (uses ucur=u[r], unext=u[r+1])
                float un = shdn1(ucur);
                float gx, gy;
                if (!EDGE) {
                    gx = un - ucur;
                    gy = unext - ucur;
                } else {
                    int gi = gi0 + r;
                    gx = gx_on ? un - ucur : 0.f;
                    gy = (gi < WID - 1) ? unext - ucur : 0.f;
                }
                float px = fmaf(0.25f, gx, px_[r]);
                float py = fmaf(0.25f, gy, py_[r]);
                float n2 = fmaf(px, px, fmaf(py, py, 1e-8f));
                float inv = fminf(rsqrtf(n2), 1.f);
                px_[r] = px * inv;
                py_[r] = py * inv;
            }
            ucur = unext;
        }
        {   // p[TVR-1]: u below unavailable -> gy=0 (halo row, don't-care)
            float un = shdn1(ucur);
            float gx = gx_on ? un - ucur : 0.f;
            float px = fmaf(0.25f, gx, px_[TVR - 1]);
            float py = py_[TVR - 1];
            float n2 = fmaf(px, px, fmaf(py, py, 1e-8f));
            float inv = fminf(rsqrtf(n2), 1.f);
            px_[TVR - 1] = px * inv;
            py_[TVR - 1] = py * inv;
        }
    }
    // final x_tv on interior rows
#pragma unroll
    for (int r = HALO; r < TVR - HALO; r++) {
        float pxm = shup1(px_[r]);
        float divx, divy;
        if (!EDGE) {
            divx = px_[r] - pxm;
            divy = py_[r] - py_[r - 1];
        } else {
            int gi = gi0 + r;
            divx = gj_le0 ? px_[r] : (gj_hi ? -pxm : px_[r] - pxm);
            divy = (gi <= 0) ? py_[r]
                 : ((gi >= WID - 1) ? -py_[r - 1] : py_[r] - py_[r - 1]);
        }
        uf[r - HALO] = z_[r] - LAM_TV * (divx + divy);
    }
}

__global__ __launch_bounds__(256) void tv_wav_fista(const float* __restrict__ zs,
                                                    float* __restrict__ x,
                                                    float* __restrict__ z,
                                                    float beta) {
    const int lane = threadIdx.x & 63;
    const int wv   = __builtin_amdgcn_readfirstlane(threadIdx.x >> 6);
    const int w    = blockIdx.x * 4 + wv;           // 32*280 = 8960 waves
    const int sl   = w / TPS;
    const int rem  = w - sl * TPS;
    const int trow = rem / TCOLS;
    const int tcol = rem - trow * TCOLS;
    const int gi0  = trow * TIR - HALO;
    const int gj   = tcol * TIC - 8 + lane;         // interior at lanes [8,56)
    const float* g = zs + (size_t)sl * HWc;

    float uf[TIR];
    const bool interior = (trow >= 1) && (trow <= TROWS - 2) &&
                          (tcol >= 1) && (tcol <= TCOLS - 2);
    if (interior) tv_core<false>(g, gi0, gj, uf);   // wave-uniform branch
    else          tv_core<true >(g, gi0, gj, uf);

    // ---- 3-level Haar + soft-threshold (replicated-lane forward) ----
    const float sc1 = (lane & 1) ? -1.f : 1.f;
    const float sc2 = (lane & 2) ? -1.f : 1.f;
    const float sc3 = (lane & 4) ? -1.f : 1.f;

    float ll1[4], lh1[4], hl1[4], hh1[4];
#pragma unroll
    for (int k = 0; k < 4; k++) {
        float a0 = uf[2 * k], a1 = uf[2 * k + 1];
        float n0 = xor_sh(a0, 1), n1 = xor_sh(a1, 1);
        float h0 = a0 + n0, d0 = sc1 * (a0 - n0);   // replicated in both lanes
        float h1 = a1 + n1, d1 = sc1 * (a1 - n1);
        ll1[k] = (h0 + h1) * 0.5f;
        lh1[k] = softt((h0 - h1) * 0.5f);
        hl1[k] = softt((d0 + d1) * 0.5f);
        hh1[k] = softt((d0 - d1) * 0.5f);
    }
    float ll2[2], lh2[2], hl2[2], hh2[2];
#pragma unroll
    for (int k = 0; k < 2; k++) {
        float a0 = ll1[2 * k], a1 = ll1[2 * k + 1];
        float n0 = xor_sh(a0, 2), n1 = xor_sh(a1, 2);
        float h0 = a0 + n0, d0 = sc2 * (a0 - n0);
        float h1 = a1 + n1, d1 = sc2 * (a1 - n1);
        ll2[k] = (h0 + h1) * 0.5f;
        lh2[k] = softt((h0 - h1) * 0.5f);
        hl2[k] = softt((d0 + d1) * 0.5f);
        hh2[k] = softt((d0 - d1) * 0.5f);
    }
    float ll3, lh3, hl3, hh3;
    {
        float a0 = ll2[0], a1 = ll2[1];
        float n0 = xor_sh(a0, 4), n1 = xor_sh(a1, 4);
        float h0 = a0 + n0, d0 = sc3 * (a0 - n0);
        float h1 = a1 + n1, d1 = sc3 * (a1 - n1);
        ll3 = (h0 + h1) * 0.5f;
        lh3 = softt((h0 - h1) * 0.5f);
        hl3 = softt((d0 + d1) * 0.5f);
        hh3 = softt((d0 - d1) * 0.5f);
    }
    // ---- inverse (shuffle-free: values replicated within blocks) ----
    float l2p[2];
    l2p[0] = 0.5f * ((ll3 + lh3) + sc3 * (hl3 + hh3));
    l2p[1] = 0.5f * ((ll3 - lh3) + sc3 * (hl3 - hh3));
    float l1p[4];
#pragma unroll
    for (int k = 0; k < 2; k++) {
        l1p[2 * k]     = 0.5f * ((l2p[k] + lh2[k]) + sc2 * (hl2[k] + hh2[k]));
        l1p[2 * k + 1] = 0.5f * ((l2p[k] - lh2[k]) + sc2 * (hl2[k] - hh2[k]));
    }
    float xn[TIR];
#pragma unroll
    for (int k = 0; k < 4; k++) {
        xn[2 * k]     = 0.5f * ((l1p[k] + lh1[k]) + sc1 * (hl1[k] + hh1[k]));
        xn[2 * k + 1] = 0.5f * ((l1p[k] - lh1[k]) + sc1 * (hl1[k] - hh1[k]));
    }

    // ---- FISTA: z = xn + beta*(xn - x_old); x = xn ----
    const bool wcol = (lane >= 8) && (lane < 56) && ((unsigned)gj < (unsigned)WID);
    float* px = x + (size_t)sl * HWc;
    float* pz = z + (size_t)sl * HWc;
    const int gi_int0 = trow * TIR;
#pragma unroll
    for (int i = 0; i < TIR; i++) {
        int off = (gi_int0 + i) * WID + gj;
        float xo = wcol ? px[off] : 0.f;
        float zn = xn[i] + beta * (xn[i] - xo);
        if (wcol) {
            px[off] = xn[i];
            pz[off] = zn;
        }
    }
}

// ---------------- host orchestration ----------------
extern "C" void kernel_launch(void* const* d_in, const int* in_sizes, int n_in,
                              void* d_out, int out_size, void* d_ws, size_t ws_size,
                              hipStream_t stream) {
    const float* y    = (const float*)d_in[0];
    const float* mask = (const float*)d_in[1];
    float* x = (float*)d_out;

    float* ws = (float*)d_ws;
    float* z  = ws;                       // NTOT
    float* t1 = ws + (size_t)NTOT;        // NTOT
    float* t2 = ws + 2 * (size_t)NTOT;    // NTOT

    const int ROW_BLKS = (NIMG * 320) / 4;      // 1280 (1 line/wave)
    const int COL_BLKS = NIMG * (WID / CB);     // 640 (8 cols, 8 waves/block)
    const int TV_BLKS  = (NSL * TPS) / 4;       // 2240

    // x0 = ifft2c(y): col-inverse then row-inverse (dual store -> x and z)
    fft_col<0><<<COL_BLKS, 512, 0, stream>>>(y, t1, nullptr, nullptr);
    fft_row<1, 3><<<ROW_BLKS, 256, 0, stream>>>(t1, x, nullptr, z);

    float t = 1.f;
    for (int it = 0; it < 15; it++) {
        // row-forward; fused (col-forward + DC + col-inverse); row-inverse
        // with residual epilogue: zs = z - g
        fft_row<-1, 0><<<ROW_BLKS, 256, 0, stream>>>(z, t1, nullptr, nullptr);
        fft_col<1><<<COL_BLKS, 512, 0, stream>>>(t1, t2, y, mask);
        fft_row<1, 2><<<ROW_BLKS, 256, 0, stream>>>(t2, t1, z, nullptr);

        // TV prox + wavelet shrinkage + FISTA momentum, one kernel
        float tn   = (1.f + sqrtf(1.f + 4.f * t * t)) * 0.5f;
        float beta = (t - 1.f) / tn;
        t = tn;
        tv_wav_fista<<<TV_BLKS, 256, 0, stream>>>(t1, x, z, beta);
    }
    (void)in_sizes; (void)n_in; (void)out_size; (void)ws_size;
}

// Round 11
// 1293.607 us; speedup vs baseline: 1.1244x; 1.1244x over previous
//
#include <hip/hip_runtime.h>
#include <math.h>

constexpr int WID  = 320;
constexpr int HWc  = 320 * 320;        // 102400
constexpr int NIMG = 16;
constexpr int NSL  = 32;               // B*C slices for TV/DWT
constexpr int NTOT = NIMG * 2 * HWc;   // 3276800 floats per full array
constexpr float LAM_TV  = 0.005f;
constexpr float LAM_WAV = 0.005f;

__device__ __forceinline__ float softt(float v) {
    float a = fmaxf(fabsf(v) - LAM_WAV, 0.f);
    return copysignf(a, v);
}

// raw v_rsq_f32: ~1ulp, single instruction. rsqrtf() lowers to the precise
// ocml path (~12 instr w/ Newton + fixups); at 75 sites/wave in the TV kernel
// that was ~1000 extra VALU instr/wave (R10 post-mortem: 4500 issued vs 1500
// hand-counted).
__device__ __forceinline__ float fast_rsq(float x) {
    float r;
    asm volatile("v_rsq_f32 %0, %1" : "=v"(r) : "v"(x));
    return r;
}

// ================= 320-point FFT core ======================================
// 320 = 5 (register DFT) x 64 (lane FFT via shfl_xor). Centered transform via
// (-1)^n modulation at load and (-1)^k at store (handled by callers).
// LESSON (R3, R6): wave-supply-bound — never trade wave count for per-wave
// ILP. LESSON (R10): DS shuffles overlap VALU at >=4 waves/SIMD — do NOT
// convert to DPP. Twiddles are lane-only -> loaded from a 3.5KB L1-hot table
// (computed once per launch) instead of 7 __sincosf calls per wave.
struct Tw { float tc, ts; float stc[6], sts[6]; };

// table layout: tb[(field)*64 + lane], fields: 0=tc 1=ts 2..7=stc 8..13=sts
__global__ void build_tw(float* tb) {
    const int lane = threadIdx.x;   // 64 threads
#pragma unroll
    for (int g = 0; g < 2; g++) {
        const float sgn = g ? 1.f : -1.f;
        float* p = tb + g * 14 * 64;
        float ts, tc;
        __sincosf(sgn * 6.283185307179586f * (float)lane / 320.f, &ts, &tc);
        p[lane] = tc; p[64 + lane] = ts;
#pragma unroll
        for (int s = 0; s < 6; s++) {
            int h = 32 >> s;
            int j = lane & (h - 1);
            float ang = sgn * 3.14159265358979323f * (float)j / (float)h;
            float ss, cc;
            __sincosf(ang, &ss, &cc);
            p[(2 + s) * 64 + lane] = cc;
            p[(8 + s) * 64 + lane] = ss;
        }
    }
}

__device__ __forceinline__ Tw load_tw(const float* __restrict__ tb, int lane) {
    Tw tw;
    tw.tc = tb[lane];
    tw.ts = tb[64 + lane];
#pragma unroll
    for (int s = 0; s < 6; s++) {
        tw.stc[s] = tb[(2 + s) * 64 + lane];
        tw.sts[s] = tb[(8 + s) * 64 + lane];
    }
    return tw;
}

// vr/vi hold elements n = lane + 64m (already sign-modulated).
// out: Cr/Ci hold X[5*bitrev6(lane) + k] in slot k (unscaled).
template<int SGN>
__device__ __forceinline__ void fft320_core(const float (&vr)[5], const float (&vi)[5],
                                            float (&Cr)[5], float (&Ci)[5],
                                            const Tw& tw, int lane) {
    const float cw1 = 0.30901699437494745f, sw1 = 0.9510565162951535f;
    const float cw2 = -0.8090169943749475f, sw2 = 0.5877852522924731f;
    const float cwt[5] = {1.f, cw1, cw2, cw2, cw1};
    const float swt[5] = {0.f, sw1, sw2, -sw2, -sw1};
    Cr[0] = vr[0] + vr[1] + vr[2] + vr[3] + vr[4];
    Ci[0] = vi[0] + vi[1] + vi[2] + vi[3] + vi[4];
#pragma unroll
    for (int k = 1; k < 5; k++) {
        float ar = vr[0], ai = vi[0];
#pragma unroll
        for (int m = 1; m < 5; m++) {
            int j = (m * k) % 5;
            float wr_ = cwt[j], wi_ = (float)SGN * swt[j];
            ar += vr[m] * wr_ - vi[m] * wi_;
            ai += vr[m] * wi_ + vi[m] * wr_;
        }
        Cr[k] = ar; Ci[k] = ai;
    }
    // twiddle W_320^{lane*k}
    float twr = 1.f, twi = 0.f;
#pragma unroll
    for (int k = 1; k < 5; k++) {
        float nr = twr * tw.tc - twi * tw.ts;
        twi = twr * tw.ts + twi * tw.tc;
        twr = nr;
        float r = Cr[k] * twr - Ci[k] * twi;
        Ci[k]   = Cr[k] * twi + Ci[k] * twr;
        Cr[k]   = r;
    }
    // 6-stage radix-2 DIF across 64 lanes
#pragma unroll
    for (int s = 0; s < 6; s++) {
        int h = 32 >> s;
        bool up = (lane & h) != 0;
#pragma unroll
        for (int k = 0; k < 5; k++) {
            float orr = __shfl_xor(Cr[k], h);
            float oii = __shfl_xor(Ci[k], h);
            if (up) {
                float dr = orr - Cr[k], di = oii - Ci[k];
                Cr[k] = dr * tw.stc[s] - di * tw.sts[s];
                Ci[k] = dr * tw.sts[s] + di * tw.stc[s];
            } else {
                Cr[k] += orr;
                Ci[k] += oii;
            }
        }
    }
}

// ---------------- row FFT pass (1 line/wave, 5120 waves = 5/SIMD) -----------
// EPI: 0 = plain store
//      2 = residual store: out = aux1 - val   (aux1 = z, PREFETCHED at entry)
//      3 = dual store:     out and out2 both get val
template<int SGN, int EPI>
__global__ __launch_bounds__(256) void fft_row(const float* __restrict__ in,
                                               float* __restrict__ out,
                                               const float* __restrict__ aux1,
                                               float* __restrict__ out2,
                                               const float* __restrict__ twb) {
    const int lane = threadIdx.x & 63;
    const int wv   = threadIdx.x >> 6;
    const int L    = blockIdx.x * 4 + wv;
    const int img  = L / 320;
    const int l    = L - img * 320;
    const size_t ibase = (size_t)img * 2 * HWc;
    const float* pre = in + ibase + (size_t)l * WID;
    const float* pim = pre + HWc;
    const int k1 = (int)(__brev((unsigned)lane) >> 26);   // bitrev6

    Tw tw = load_tw(twb, lane);   // L1-hot, issues before/with input loads

    float vr[5], vi[5];
    const float sgn_in = (lane & 1) ? -1.f : 1.f;
#pragma unroll
    for (int m = 0; m < 5; m++) {
        int n = lane + 64 * m;
        vr[m] = sgn_in * pre[n];
        vi[m] = sgn_in * pim[n];
    }
    // prefetch residual operand (z) before the latency-heavy core
    float zr[5], zi[5];
    if (EPI == 2) {
#pragma unroll
        for (int k = 0; k < 5; k++) {
            int idxs = 5 * k1 + k + l * WID;
            zr[k] = aux1[ibase + idxs];
            zi[k] = aux1[ibase + HWc + idxs];
        }
    }

    float Cr[5], Ci[5];
    fft320_core<SGN>(vr, vi, Cr, Ci, tw, lane);

    float* qre = out + ibase + (size_t)l * WID;
    float* qim = qre + HWc;
    const float scale = 0.05590169943749474f;  // 1/sqrt(320)
#pragma unroll
    for (int k = 0; k < 5; k++) {
        int kout = 5 * k1 + k;
        float s2 = (kout & 1) ? -scale : scale;
        float re = s2 * Cr[k];
        float im = s2 * Ci[k];
        const int idxs = kout + l * WID;
        if (EPI == 2) {
            re = zr[k] - re;
            im = zi[k] - im;
        }
        qre[kout] = re;
        qim[kout] = im;
        if (EPI == 3) {
            out2[ibase + idxs]       = re;
            out2[ibase + HWc + idxs] = im;
        }
    }
}

// ---------------- fused column FFT kernel (LDS-transposed, high-TLP) --------
// Block = 512 threads (8 waves) handles 8 complex columns; ONE column line
// per wave per pass -> 640 blocks x 8 = 5120 waves (5/SIMD).
// Tile [comp][row 320][9]: stride 9, gcd(9,32)=1 -> 2-way LDS aliasing (free).
// MODE 0: single inverse column FFT (init path).
// MODE 1: forward col FFT + k-space DC (m*(m*K - y)) + inverse col FFT.
constexpr int CB   = 8;        // columns per block
constexpr int CPAD = CB + 1;   // 9

template<int SGN>
__device__ __forceinline__ void fft_line_lds(float (*tile)[320][CPAD], int cl,
                                             int lane, const Tw& tw) {
    float vr[5], vi[5], Cr[5], Ci[5];
    const float sgn_in = (lane & 1) ? -1.f : 1.f;
#pragma unroll
    for (int m = 0; m < 5; m++) {
        int n = lane + 64 * m;
        vr[m] = sgn_in * tile[0][n][cl];
        vi[m] = sgn_in * tile[1][n][cl];
    }
    fft320_core<SGN>(vr, vi, Cr, Ci, tw, lane);
    const int k1 = (int)(__brev((unsigned)lane) >> 26);
    const float scale = 0.05590169943749474f;
#pragma unroll
    for (int k = 0; k < 5; k++) {
        int kout = 5 * k1 + k;
        float s2 = (kout & 1) ? -scale : scale;
        tile[0][kout][cl] = s2 * Cr[k];
        tile[1][kout][cl] = s2 * Ci[k];
    }
}

template<int MODE>
__global__ __launch_bounds__(512) void fft_col(const float* __restrict__ in,
                                               float* __restrict__ out,
                                               const float* __restrict__ y,
                                               const float* __restrict__ mask,
                                               const float* __restrict__ twb) {
    __shared__ float tile[2][320][CPAD];   // 23 KB
    const int tid = threadIdx.x;
    const int bpi = WID / CB;              // 40 blocks per image
    const int img = blockIdx.x / bpi;
    const int c0  = (blockIdx.x - img * bpi) * CB;
    const size_t ibase = (size_t)img * 2 * HWc;
    constexpr int C4 = CB / 4;             // 2 float4 groups per row
    constexpr int NE = 320 * C4;           // 640 float4 per component

#pragma unroll
    for (int comp = 0; comp < 2; comp++) {
        const float* p = in + ibase + (size_t)comp * HWc + c0;
        for (int i = tid; i < NE; i += 512) {
            int row = i >> 1, cg = (i & 1) << 2;
            float4 v = *(const float4*)(p + row * WID + cg);
            float* t = &tile[comp][row][cg];
            t[0] = v.x; t[1] = v.y; t[2] = v.z; t[3] = v.w;
        }
    }
    __syncthreads();

    const int lane = tid & 63;
    const int wv   = tid >> 6;             // wave = column index [0,8)

    if (MODE == 1) {
        Tw twf = load_tw(twb, lane);              // forward table
        fft_line_lds<-1>(tile, wv, lane, twf);
        __syncthreads();
        // k-space data consistency, all streams coalesced
        const float* pm  = mask + (size_t)img * HWc + c0;
        const float* pyr = y + ibase + c0;
        const float* pyi = y + ibase + HWc + c0;
        for (int i = tid; i < NE; i += 512) {
            int row = i >> 1, cg = (i & 1) << 2;
            float4 m4 = *(const float4*)(pm  + row * WID + cg);
            float4 yr = *(const float4*)(pyr + row * WID + cg);
            float4 yi = *(const float4*)(pyi + row * WID + cg);
            float* tr = &tile[0][row][cg];
            float* ti = &tile[1][row][cg];
            tr[0] = m4.x * (m4.x * tr[0] - yr.x);
            tr[1] = m4.y * (m4.y * tr[1] - yr.y);
            tr[2] = m4.z * (m4.z * tr[2] - yr.z);
            tr[3] = m4.w * (m4.w * tr[3] - yr.w);
            ti[0] = m4.x * (m4.x * ti[0] - yi.x);
            ti[1] = m4.y * (m4.y * ti[1] - yi.y);
            ti[2] = m4.z * (m4.z * ti[2] - yi.z);
            ti[3] = m4.w * (m4.w * ti[3] - yi.w);
        }
        __syncthreads();
    }
    {
        Tw twi = load_tw(twb + 14 * 64, lane);    // inverse table
        fft_line_lds<1>(tile, wv, lane, twi);
    }
    __syncthreads();
#pragma unroll
    for (int comp = 0; comp < 2; comp++) {
        float* p = out + ibase + (size_t)comp * HWc + c0;
        for (int i = tid; i < NE; i += 512) {
            int row = i >> 1, cg = (i & 1) << 2;
            const float* t = &tile[comp][row][cg];
            *(float4*)(p + row * WID + cg) = make_float4(t[0], t[1], t[2], t[3]);
        }
    }
}

// ============ fused TV prox + 3-level Haar shrinkage + FISTA ================
// One WAVE per tile: interior 8 rows x 48 cols (8x8-block aligned), halo 8
// cols each side (lane = col, interior lanes [8,56)), vertical halo 4 rows.
// TIR=8/halo=4: state 3x16=48 floats fits ~48 VGPR, no AGPR spill, 8960
// waves (8.75/SIMD). Rolling-u pipeline; edge/interior templated; raw
// v_rsq_f32 (R11). Halo-4 error ~(lam*tau*k)^4 ~ 1e-9 at interior.
constexpr int HALO = 4;
constexpr int TIR = 8;                  // interior rows
constexpr int TVR = TIR + 2 * HALO;     // 16 rows per tile
constexpr int TIC = 48;                 // interior cols
constexpr int TCOLS = 7;                // ceil(320/48), last tile interior 32
constexpr int TROWS = WID / TIR;        // 40
constexpr int TPS = TROWS * TCOLS;      // 280 tiles per slice

template<bool EDGE>
__device__ __forceinline__ void tv_core(const float* __restrict__ g, int gi0, int gj,
                                        float (&uf)[TIR]) {
    float z_[TVR], px_[TVR], py_[TVR];
    const bool colin = !EDGE || ((unsigned)gj < (unsigned)WID);
#pragma unroll
    for (int r = 0; r < TVR; r++) {
        int gi = gi0 + r;
        float v = 0.f;
        if (!EDGE) {
            v = g[gi * WID + gj];
        } else {
            bool in = colin && ((unsigned)gi < (unsigned)WID);
            if (in) v = g[gi * WID + gj];
        }
        z_[r] = v; px_[r] = 0.f; py_[r] = 0.f;
    }
    const bool gj_le0 = EDGE && (gj <= 0);
    const bool gj_hi  = EDGE && (gj >= WID - 1);
    const bool gx_on  = !EDGE || (gj < WID - 1);

#pragma clang loop unroll(disable)
    for (int it = 0; it < 5; it++) {
        float ucur, unext;
        {   // u[0] (halo row; divy value don't-care for interior output)
            float pxm = __shfl_up(px_[0], 1);
            float divx, divy;
            if (!EDGE) {
                divx = px_[0] - pxm;
                divy = 0.f;
            } else {
                int gi = gi0;
                divx = gj_le0 ? px_[0] : (gj_hi ? -pxm : px_[0] - pxm);
                divy = (gi <= 0) ? py_[0] : ((gi >= WID - 1) ? -py_[0] : 0.f);
            }
            ucur = z_[0] - LAM_TV * (divx + divy);
        }
#pragma unroll
        for (int r = 0; r < TVR - 1; r++) {
            {   // unext = u[r+1] from OLD p (p rows >= r not yet updated)
                float pxm = __shfl_up(px_[r + 1], 1);
                float divx, divy;
                if (!EDGE) {
                    divx = px_[r + 1] - pxm;
                    divy = py_[r + 1] - py_[r];
                } else {
                    int gi1 = gi0 + r + 1;
                    divx = gj_le0 ? px_[r + 1] : (gj_hi ? -pxm : px_[r + 1] - pxm);
                    divy = (gi1 <= 0) ? py_[r + 1]
                         : ((gi1 >= WID - 1) ? -py_[r] : py_[r + 1] - py_[r]);
                }
                unext = z_[r + 1] - LAM_TV * (divx + divy);
            }
            {   // p[r] update (uses ucur=u[r], unext=u[r+1])
                float un = __shfl_down(ucur, 1);
                float gx, gy;
                if (!EDGE) {
                    gx = un - ucur;
                    gy = unext - ucur;
                } else {
                    int gi = gi0 + r;
                    gx = gx_on ? un - ucur : 0.f;
                    gy = (gi < WID - 1) ? unext - ucur : 0.f;
                }
                float px = fmaf(0.25f, gx, px_[r]);
                float py = fmaf(0.25f, gy, py_[r]);
                float n2 = fmaf(px, px, fmaf(py, py, 1e-8f));
                float inv = fminf(fast_rsq(n2), 1.f);
                px_[r] = px * inv;
                py_[r] = py * inv;
            }
            ucur = unext;
        }
        {   // p[TVR-1]: u below unavailable -> gy=0 (halo row, don't-care)
            float un = __shfl_down(ucur, 1);
            float gx = gx_on ? un - ucur : 0.f;
            float px = fmaf(0.25f, gx, px_[TVR - 1]);
            float py = py_[TVR - 1];
            float n2 = fmaf(px, px, fmaf(py, py, 1e-8f));
            float inv = fminf(fast_rsq(n2), 1.f);
            px_[TVR - 1] = px * inv;
            py_[TVR - 1] = py * inv;
        }
    }
    // final x_tv on interior rows
#pragma unroll
    for (int r = HALO; r < TVR - HALO; r++) {
        float pxm = __shfl_up(px_[r], 1);
        float divx, divy;
        if (!EDGE) {
            divx = px_[r] - pxm;
            divy = py_[r] - py_[r - 1];
        } else {
            int gi = gi0 + r;
            divx = gj_le0 ? px_[r] : (gj_hi ? -pxm : px_[r] - pxm);
            divy = (gi <= 0) ? py_[r]
                 : ((gi >= WID - 1) ? -py_[r - 1] : py_[r] - py_[r - 1]);
        }
        uf[r - HALO] = z_[r] - LAM_TV * (divx + divy);
    }
}

__global__ __launch_bounds__(256) void tv_wav_fista(const float* __restrict__ zs,
                                                    float* __restrict__ x,
                                                    float* __restrict__ z,
                                                    float beta) {
    const int lane = threadIdx.x & 63;
    const int wv   = __builtin_amdgcn_readfirstlane(threadIdx.x >> 6);
    const int w    = blockIdx.x * 4 + wv;           // 32*280 = 8960 waves
    const int sl   = w / TPS;
    const int rem  = w - sl * TPS;
    const int trow = rem / TCOLS;
    const int tcol = rem - trow * TCOLS;
    const int gi0  = trow * TIR - HALO;
    const int gj   = tcol * TIC - 8 + lane;         // interior at lanes [8,56)
    const float* g = zs + (size_t)sl * HWc;

    float uf[TIR];
    const bool interior = (trow >= 1) && (trow <= TROWS - 2) &&
                          (tcol >= 1) && (tcol <= TCOLS - 2);
    if (interior) tv_core<false>(g, gi0, gj, uf);   // wave-uniform branch
    else          tv_core<true >(g, gi0, gj, uf);

    // ---- 3-level Haar + soft-threshold (replicated-lane forward) ----
    const float sc1 = (lane & 1) ? -1.f : 1.f;
    const float sc2 = (lane & 2) ? -1.f : 1.f;
    const float sc3 = (lane & 4) ? -1.f : 1.f;

    float ll1[4], lh1[4], hl1[4], hh1[4];
#pragma unroll
    for (int k = 0; k < 4; k++) {
        float a0 = uf[2 * k], a1 = uf[2 * k + 1];
        float n0 = __shfl_xor(a0, 1), n1 = __shfl_xor(a1, 1);
        float h0 = a0 + n0, d0 = sc1 * (a0 - n0);   // replicated in both lanes
        float h1 = a1 + n1, d1 = sc1 * (a1 - n1);
        ll1[k] = (h0 + h1) * 0.5f;
        lh1[k] = softt((h0 - h1) * 0.5f);
        hl1[k] = softt((d0 + d1) * 0.5f);
        hh1[k] = softt((d0 - d1) * 0.5f);
    }
    float ll2[2], lh2[2], hl2[2], hh2[2];
#pragma unroll
    for (int k = 0; k < 2; k++) {
        float a0 = ll1[2 * k], a1 = ll1[2 * k + 1];
        float n0 = __shfl_xor(a0, 2), n1 = __shfl_xor(a1, 2);
        float h0 = a0 + n0, d0 = sc2 * (a0 - n0);
        float h1 = a1 + n1, d1 = sc2 * (a1 - n1);
        ll2[k] = (h0 + h1) * 0.5f;
        lh2[k] = softt((h0 - h1) * 0.5f);
        hl2[k] = softt((d0 + d1) * 0.5f);
        hh2[k] = softt((d0 - d1) * 0.5f);
    }
    float ll3, lh3, hl3, hh3;
    {
        float a0 = ll2[0], a1 = ll2[1];
        float n0 = __shfl_xor(a0, 4), n1 = __shfl_xor(a1, 4);
        float h0 = a0 + n0, d0 = sc3 * (a0 - n0);
        float h1 = a1 + n1, d1 = sc3 * (a1 - n1);
        ll3 = (h0 + h1) * 0.5f;
        lh3 = softt((h0 - h1) * 0.5f);
        hl3 = softt((d0 + d1) * 0.5f);
        hh3 = softt((d0 - d1) * 0.5f);
    }
    // ---- inverse (shuffle-free: values replicated within blocks) ----
    float l2p[2];
    l2p[0] = 0.5f * ((ll3 + lh3) + sc3 * (hl3 + hh3));
    l2p[1] = 0.5f * ((ll3 - lh3) + sc3 * (hl3 - hh3));
    float l1p[4];
#pragma unroll
    for (int k = 0; k < 2; k++) {
        l1p[2 * k]     = 0.5f * ((l2p[k] + lh2[k]) + sc2 * (hl2[k] + hh2[k]));
        l1p[2 * k + 1] = 0.5f * ((l2p[k] - lh2[k]) + sc2 * (hl2[k] - hh2[k]));
    }
    float xn[TIR];
#pragma unroll
    for (int k = 0; k < 4; k++) {
        xn[2 * k]     = 0.5f * ((l1p[k] + lh1[k]) + sc1 * (hl1[k] + hh1[k]));
        xn[2 * k + 1] = 0.5f * ((l1p[k] - lh1[k]) + sc1 * (hl1[k] - hh1[k]));
    }

    // ---- FISTA: z = xn + beta*(xn - x_old); x = xn ----
    const bool wcol = (lane >= 8) && (lane < 56) && ((unsigned)gj < (unsigned)WID);
    float* px = x + (size_t)sl * HWc;
    float* pz = z + (size_t)sl * HWc;
    const int gi_int0 = trow * TIR;
#pragma unroll
    for (int i = 0; i < TIR; i++) {
        int off = (gi_int0 + i) * WID + gj;
        float xo = wcol ? px[off] : 0.f;
        float zn = xn[i] + beta * (xn[i] - xo);
        if (wcol) {
            px[off] = xn[i];
            pz[off] = zn;
        }
    }
}

// ---------------- host orchestration ----------------
extern "C" void kernel_launch(void* const* d_in, const int* in_sizes, int n_in,
                              void* d_out, int out_size, void* d_ws, size_t ws_size,
                              hipStream_t stream) {
    const float* y    = (const float*)d_in[0];
    const float* mask = (const float*)d_in[1];
    float* x = (float*)d_out;

    float* ws = (float*)d_ws;
    float* z  = ws;                       // NTOT
    float* t1 = ws + (size_t)NTOT;        // NTOT
    float* t2 = ws + 2 * (size_t)NTOT;    // NTOT
    float* tw = ws + 3 * (size_t)NTOT;    // 2*14*64 floats twiddle tables
    float* twF = tw;                      // forward (SGN=-1)
    float* twI = tw + 14 * 64;            // inverse (SGN=+1)

    const int ROW_BLKS = (NIMG * 320) / 4;      // 1280 (1 line/wave)
    const int COL_BLKS = NIMG * (WID / CB);     // 640 (8 cols, 8 waves/block)
    const int TV_BLKS  = (NSL * TPS) / 4;       // 2240

    build_tw<<<1, 64, 0, stream>>>(tw);

    // x0 = ifft2c(y): col-inverse then row-inverse (dual store -> x and z)
    fft_col<0><<<COL_BLKS, 512, 0, stream>>>(y, t1, nullptr, nullptr, twF);
    fft_row<1, 3><<<ROW_BLKS, 256, 0, stream>>>(t1, x, nullptr, z, twI);

    float t = 1.f;
    for (int it = 0; it < 15; it++) {
        // row-forward; fused (col-forward + DC + col-inverse); row-inverse
        // with residual epilogue: zs = z - g
        fft_row<-1, 0><<<ROW_BLKS, 256, 0, stream>>>(z, t1, nullptr, nullptr, twF);
        fft_col<1><<<COL_BLKS, 512, 0, stream>>>(t1, t2, y, mask, twF);
        fft_row<1, 2><<<ROW_BLKS, 256, 0, stream>>>(t2, t1, z, nullptr, twI);

        // TV prox + wavelet shrinkage + FISTA momentum, one kernel
        float tn   = (1.f + sqrtf(1.f + 4.f * t * t)) * 0.5f;
        float beta = (t - 1.f) / tn;
        t = tn;
        tv_wav_fista<<<TV_BLKS, 256, 0, stream>>>(t1, x, z, beta);
    }
    (void)in_sizes; (void)n_in; (void)out_size; (void)ws_size;
}

// Round 12
// 1277.608 us; speedup vs baseline: 1.1385x; 1.0125x over previous
//
#include <hip/hip_runtime.h>
#include <math.h>

constexpr int WID  = 320;
constexpr int HWc  = 320 * 320;        // 102400
constexpr int NIMG = 16;
constexpr int NSL  = 32;               // B*C slices for TV/DWT
constexpr int NTOT = NIMG * 2 * HWc;   // 3276800 floats per full array
constexpr float LAM_TV  = 0.005f;
constexpr float LAM_WAV = 0.005f;

__device__ __forceinline__ float softt(float v) {
    float a = fmaxf(fabsf(v) - LAM_WAV, 0.f);
    return copysignf(a, v);
}

// raw v_rsq_f32: ~1ulp, single instruction (rsqrtf can lower to the precise
// ocml multi-instruction path).
__device__ __forceinline__ float fast_rsq(float x) {
    float r;
    asm volatile("v_rsq_f32 %0, %1" : "=v"(r) : "v"(x));
    return r;
}

// ================= 320-point FFT core ======================================
// 320 = 5 (register DFT) x 64 (lane FFT via shfl_xor). Centered transform via
// (-1)^n modulation at load and (-1)^k at store (handled by callers).
// LESSONS: (R3,R6) wave-supply-bound — never trade wave count for ILP.
// (R10) DS shuffles overlap VALU at >=4 waves/SIMD — do NOT convert to DPP.
// (R11) twiddles from a 3.5KB L1-hot table, not __sincosf.
struct Tw { float tc, ts; float stc[6], sts[6]; };

// table layout: tb[(field)*64 + lane], fields: 0=tc 1=ts 2..7=stc 8..13=sts
__global__ void build_tw(float* tb) {
    const int lane = threadIdx.x;   // 64 threads
#pragma unroll
    for (int g = 0; g < 2; g++) {
        const float sgn = g ? 1.f : -1.f;
        float* p = tb + g * 14 * 64;
        float ts, tc;
        __sincosf(sgn * 6.283185307179586f * (float)lane / 320.f, &ts, &tc);
        p[lane] = tc; p[64 + lane] = ts;
#pragma unroll
        for (int s = 0; s < 6; s++) {
            int h = 32 >> s;
            int j = lane & (h - 1);
            float ang = sgn * 3.14159265358979323f * (float)j / (float)h;
            float ss, cc;
            __sincosf(ang, &ss, &cc);
            p[(2 + s) * 64 + lane] = cc;
            p[(8 + s) * 64 + lane] = ss;
        }
    }
}

__device__ __forceinline__ Tw load_tw(const float* __restrict__ tb, int lane) {
    Tw tw;
    tw.tc = tb[lane];
    tw.ts = tb[64 + lane];
#pragma unroll
    for (int s = 0; s < 6; s++) {
        tw.stc[s] = tb[(2 + s) * 64 + lane];
        tw.sts[s] = tb[(8 + s) * 64 + lane];
    }
    return tw;
}

// vr/vi hold elements n = lane + 64m (already sign-modulated).
// out: Cr/Ci hold X[5*bitrev6(lane) + k] in slot k (unscaled).
template<int SGN>
__device__ __forceinline__ void fft320_core(const float (&vr)[5], const float (&vi)[5],
                                            float (&Cr)[5], float (&Ci)[5],
                                            const Tw& tw, int lane) {
    const float cw1 = 0.30901699437494745f, sw1 = 0.9510565162951535f;
    const float cw2 = -0.8090169943749475f, sw2 = 0.5877852522924731f;
    const float cwt[5] = {1.f, cw1, cw2, cw2, cw1};
    const float swt[5] = {0.f, sw1, sw2, -sw2, -sw1};
    Cr[0] = vr[0] + vr[1] + vr[2] + vr[3] + vr[4];
    Ci[0] = vi[0] + vi[1] + vi[2] + vi[3] + vi[4];
#pragma unroll
    for (int k = 1; k < 5; k++) {
        float ar = vr[0], ai = vi[0];
#pragma unroll
        for (int m = 1; m < 5; m++) {
            int j = (m * k) % 5;
            float wr_ = cwt[j], wi_ = (float)SGN * swt[j];
            ar += vr[m] * wr_ - vi[m] * wi_;
            ai += vr[m] * wi_ + vi[m] * wr_;
        }
        Cr[k] = ar; Ci[k] = ai;
    }
    // twiddle W_320^{lane*k}
    float twr = 1.f, twi = 0.f;
#pragma unroll
    for (int k = 1; k < 5; k++) {
        float nr = twr * tw.tc - twi * tw.ts;
        twi = twr * tw.ts + twi * tw.tc;
        twr = nr;
        float r = Cr[k] * twr - Ci[k] * twi;
        Ci[k]   = Cr[k] * twi + Ci[k] * twr;
        Cr[k]   = r;
    }
    // 6-stage radix-2 DIF across 64 lanes
#pragma unroll
    for (int s = 0; s < 6; s++) {
        int h = 32 >> s;
        bool up = (lane & h) != 0;
#pragma unroll
        for (int k = 0; k < 5; k++) {
            float orr = __shfl_xor(Cr[k], h);
            float oii = __shfl_xor(Ci[k], h);
            if (up) {
                float dr = orr - Cr[k], di = oii - Ci[k];
                Cr[k] = dr * tw.stc[s] - di * tw.sts[s];
                Ci[k] = dr * tw.sts[s] + di * tw.stc[s];
            } else {
                Cr[k] += orr;
                Ci[k] += oii;
            }
        }
    }
}

// ---------------- row FFT pass (1 line/wave, 5120 waves = 5/SIMD) -----------
// EPI: 0 = plain store
//      2 = residual store: out = aux1 - val   (aux1 = z, PREFETCHED at entry)
//      3 = dual store:     out and out2 both get val
template<int SGN, int EPI>
__global__ __launch_bounds__(256) void fft_row(const float* __restrict__ in,
                                               float* __restrict__ out,
                                               const float* __restrict__ aux1,
                                               float* __restrict__ out2,
                                               const float* __restrict__ twb) {
    const int lane = threadIdx.x & 63;
    const int wv   = threadIdx.x >> 6;
    const int L    = blockIdx.x * 4 + wv;
    const int img  = L / 320;
    const int l    = L - img * 320;
    const size_t ibase = (size_t)img * 2 * HWc;
    const float* pre = in + ibase + (size_t)l * WID;
    const float* pim = pre + HWc;
    const int k1 = (int)(__brev((unsigned)lane) >> 26);   // bitrev6

    Tw tw = load_tw(twb, lane);   // L1-hot, issues before/with input loads

    float vr[5], vi[5];
    const float sgn_in = (lane & 1) ? -1.f : 1.f;
#pragma unroll
    for (int m = 0; m < 5; m++) {
        int n = lane + 64 * m;
        vr[m] = sgn_in * pre[n];
        vi[m] = sgn_in * pim[n];
    }
    // prefetch residual operand (z) before the latency-heavy core
    float zr[5], zi[5];
    if (EPI == 2) {
#pragma unroll
        for (int k = 0; k < 5; k++) {
            int idxs = 5 * k1 + k + l * WID;
            zr[k] = aux1[ibase + idxs];
            zi[k] = aux1[ibase + HWc + idxs];
        }
    }

    float Cr[5], Ci[5];
    fft320_core<SGN>(vr, vi, Cr, Ci, tw, lane);

    float* qre = out + ibase + (size_t)l * WID;
    float* qim = qre + HWc;
    const float scale = 0.05590169943749474f;  // 1/sqrt(320)
#pragma unroll
    for (int k = 0; k < 5; k++) {
        int kout = 5 * k1 + k;
        float s2 = (kout & 1) ? -scale : scale;
        float re = s2 * Cr[k];
        float im = s2 * Ci[k];
        const int idxs = kout + l * WID;
        if (EPI == 2) {
            re = zr[k] - re;
            im = zi[k] - im;
        }
        qre[kout] = re;
        qim[kout] = im;
        if (EPI == 3) {
            out2[ibase + idxs]       = re;
            out2[ibase + HWc + idxs] = im;
        }
    }
}

// ---------------- fused column FFT kernel (LDS-transposed, high-TLP) --------
// Block = 512 threads (8 waves) handles 8 complex columns; ONE column line
// per wave per pass -> 640 blocks x 8 = 5120 waves (5/SIMD).
// Tile [comp][row 320][9]: stride 9, gcd(9,32)=1 -> 2-way LDS aliasing (free).
// MODE 0: single inverse column FFT (init path).
// MODE 1: forward col FFT + k-space DC (m*(m*K - y)) + inverse col FFT.
constexpr int CB   = 8;        // columns per block
constexpr int CPAD = CB + 1;   // 9

template<int SGN>
__device__ __forceinline__ void fft_line_lds(float (*tile)[320][CPAD], int cl,
                                             int lane, const Tw& tw) {
    float vr[5], vi[5], Cr[5], Ci[5];
    const float sgn_in = (lane & 1) ? -1.f : 1.f;
#pragma unroll
    for (int m = 0; m < 5; m++) {
        int n = lane + 64 * m;
        vr[m] = sgn_in * tile[0][n][cl];
        vi[m] = sgn_in * tile[1][n][cl];
    }
    fft320_core<SGN>(vr, vi, Cr, Ci, tw, lane);
    const int k1 = (int)(__brev((unsigned)lane) >> 26);
    const float scale = 0.05590169943749474f;
#pragma unroll
    for (int k = 0; k < 5; k++) {
        int kout = 5 * k1 + k;
        float s2 = (kout & 1) ? -scale : scale;
        tile[0][kout][cl] = s2 * Cr[k];
        tile[1][kout][cl] = s2 * Ci[k];
    }
}

template<int MODE>
__global__ __launch_bounds__(512) void fft_col(const float* __restrict__ in,
                                               float* __restrict__ out,
                                               const float* __restrict__ y,
                                               const float* __restrict__ mask,
                                               const float* __restrict__ twb) {
    __shared__ float tile[2][320][CPAD];   // 23 KB
    const int tid = threadIdx.x;
    const int bpi = WID / CB;              // 40 blocks per image
    const int img = blockIdx.x / bpi;
    const int c0  = (blockIdx.x - img * bpi) * CB;
    const size_t ibase = (size_t)img * 2 * HWc;
    constexpr int C4 = CB / 4;             // 2 float4 groups per row
    constexpr int NE = 320 * C4;           // 640 float4 per component

#pragma unroll
    for (int comp = 0; comp < 2; comp++) {
        const float* p = in + ibase + (size_t)comp * HWc + c0;
        for (int i = tid; i < NE; i += 512) {
            int row = i >> 1, cg = (i & 1) << 2;
            float4 v = *(const float4*)(p + row * WID + cg);
            float* t = &tile[comp][row][cg];
            t[0] = v.x; t[1] = v.y; t[2] = v.z; t[3] = v.w;
        }
    }
    __syncthreads();

    const int lane = tid & 63;
    const int wv   = tid >> 6;             // wave = column index [0,8)

    if (MODE == 1) {
        Tw twf = load_tw(twb, lane);              // forward table
        fft_line_lds<-1>(tile, wv, lane, twf);
        __syncthreads();
        // k-space data consistency, all streams coalesced
        const float* pm  = mask + (size_t)img * HWc + c0;
        const float* pyr = y + ibase + c0;
        const float* pyi = y + ibase + HWc + c0;
        for (int i = tid; i < NE; i += 512) {
            int row = i >> 1, cg = (i & 1) << 2;
            float4 m4 = *(const float4*)(pm  + row * WID + cg);
            float4 yr = *(const float4*)(pyr + row * WID + cg);
            float4 yi = *(const float4*)(pyi + row * WID + cg);
            float* tr = &tile[0][row][cg];
            float* ti = &tile[1][row][cg];
            tr[0] = m4.x * (m4.x * tr[0] - yr.x);
            tr[1] = m4.y * (m4.y * tr[1] - yr.y);
            tr[2] = m4.z * (m4.z * tr[2] - yr.z);
            tr[3] = m4.w * (m4.w * tr[3] - yr.w);
            ti[0] = m4.x * (m4.x * ti[0] - yi.x);
            ti[1] = m4.y * (m4.y * ti[1] - yi.y);
            ti[2] = m4.z * (m4.z * ti[2] - yi.z);
            ti[3] = m4.w * (m4.w * ti[3] - yi.w);
        }
        __syncthreads();
    }
    {
        Tw twi = load_tw(twb + 14 * 64, lane);    // inverse table
        fft_line_lds<1>(tile, wv, lane, twi);
    }
    __syncthreads();
#pragma unroll
    for (int comp = 0; comp < 2; comp++) {
        float* p = out + ibase + (size_t)comp * HWc + c0;
        for (int i = tid; i < NE; i += 512) {
            int row = i >> 1, cg = (i & 1) << 2;
            const float* t = &tile[comp][row][cg];
            *(float4*)(p + row * WID + cg) = make_float4(t[0], t[1], t[2], t[3]);
        }
    }
}

// ============ fused TV prox + 3-level Haar shrinkage + FISTA ================
// One WAVE per tile: interior 8 rows x 48 cols, halo 8 cols / 4 rows.
// R12: SPLIT-PASS dual iterations — all 16 shfl_up(px) issued together, then
// all u's, then all 16 shfl_down(u), then all p-updates. Batches the DS
// latency (~35cyc/op) that the rolling-u chain serialized (TV stuck at 44-54us
// across R4..R11 regardless of VGPR/waves/DPP -> DS-chain hypothesis). At
// TVR=16 the split state (~80 floats) fits ~100 VGPR without the AGPR spill
// that killed R7's TVR=26 attempt. Edge tiles dispatched FIRST (they run the
// heavier path; launching them early hides them behind interior waves).
constexpr int HALO = 4;
constexpr int TIR = 8;                  // interior rows
constexpr int TVR = TIR + 2 * HALO;     // 16 rows per tile
constexpr int TIC = 48;                 // interior cols
constexpr int TCOLS = 7;                // ceil(320/48), last tile interior 32
constexpr int TROWS = WID / TIR;        // 40
constexpr int TPS = TROWS * TCOLS;      // 280 tiles per slice
constexpr int NEDGE = 2 * TCOLS + 2 * (TROWS - 2);   // 90 edge tiles/slice

template<bool EDGE>
__device__ __forceinline__ void tv_core(const float* __restrict__ g, int gi0, int gj,
                                        float (&uf)[TIR]) {
    float z_[TVR], px_[TVR], py_[TVR];
    const bool colin = !EDGE || ((unsigned)gj < (unsigned)WID);
#pragma unroll
    for (int r = 0; r < TVR; r++) {
        int gi = gi0 + r;
        float v = 0.f;
        if (!EDGE) {
            v = g[gi * WID + gj];
        } else {
            bool in = colin && ((unsigned)gi < (unsigned)WID);
            if (in) v = g[gi * WID + gj];
        }
        z_[r] = v; px_[r] = 0.f; py_[r] = 0.f;
    }
    const bool gj_le0 = EDGE && (gj <= 0);
    const bool gj_hi  = EDGE && (gj >= WID - 1);
    const bool gx_on  = !EDGE || (gj < WID - 1);

#pragma clang loop unroll(disable)
    for (int it = 0; it < 5; it++) {
        float u_[TVR], sh[TVR];
        // batch 1: all shfl_up(px) issued back-to-back (independent DS ops)
#pragma unroll
        for (int r = 0; r < TVR; r++) sh[r] = __shfl_up(px_[r], 1);
        // u[r] = z[r] - lam*div(p)[r]  (old p; rows independent)
#pragma unroll
        for (int r = 0; r < TVR; r++) {
            float divx, divy;
            if (!EDGE) {
                divx = px_[r] - sh[r];
                divy = (r > 0) ? py_[r] - py_[r - 1] : 0.f;  // r=0 halo: don't-care
            } else {
                int gi = gi0 + r;
                divx = gj_le0 ? px_[r] : (gj_hi ? -sh[r] : px_[r] - sh[r]);
                float pym = (r > 0) ? py_[r - 1] : py_[0];
                divy = (gi <= 0) ? py_[r]
                     : ((gi >= WID - 1) ? -pym : py_[r] - pym);
            }
            u_[r] = z_[r] - LAM_TV * (divx + divy);
        }
        // batch 2: all shfl_down(u) issued back-to-back
#pragma unroll
        for (int r = 0; r < TVR; r++) sh[r] = __shfl_down(u_[r], 1);
        // p[r] = proj(p[r] + tau*grad(u)[r])  (rows independent)
#pragma unroll
        for (int r = 0; r < TVR; r++) {
            float gx, gy;
            if (!EDGE) {
                gx = sh[r] - u_[r];
                gy = (r < TVR - 1) ? u_[r + 1] - u_[r] : 0.f;  // last row halo
            } else {
                int gi = gi0 + r;
                float ub = (r < TVR - 1) ? u_[r + 1] : u_[r];
                gx = gx_on ? sh[r] - u_[r] : 0.f;
                gy = (gi < WID - 1 && r < TVR - 1) ? ub - u_[r] : 0.f;
            }
            float px = fmaf(0.25f, gx, px_[r]);
            float py = fmaf(0.25f, gy, py_[r]);
            float n2 = fmaf(px, px, fmaf(py, py, 1e-8f));
            float inv = fminf(fast_rsq(n2), 1.f);
            px_[r] = px * inv;
            py_[r] = py * inv;
        }
    }
    // final x_tv on interior rows (batch the shfl_ups here too)
    float shf[TIR];
#pragma unroll
    for (int r = HALO; r < TVR - HALO; r++) shf[r - HALO] = __shfl_up(px_[r], 1);
#pragma unroll
    for (int r = HALO; r < TVR - HALO; r++) {
        float pxm = shf[r - HALO];
        float divx, divy;
        if (!EDGE) {
            divx = px_[r] - pxm;
            divy = py_[r] - py_[r - 1];
        } else {
            int gi = gi0 + r;
            divx = gj_le0 ? px_[r] : (gj_hi ? -pxm : px_[r] - pxm);
            divy = (gi <= 0) ? py_[r]
                 : ((gi >= WID - 1) ? -py_[r - 1] : py_[r] - py_[r - 1]);
        }
        uf[r - HALO] = z_[r] - LAM_TV * (divx + divy);
    }
}

template<bool STOREZ>
__global__ __launch_bounds__(256) void tv_wav_fista(const float* __restrict__ zs,
                                                    float* __restrict__ x,
                                                    float* __restrict__ z,
                                                    float beta) {
    const int lane = threadIdx.x & 63;
    const int wv   = __builtin_amdgcn_readfirstlane(threadIdx.x >> 6);
    const int w    = blockIdx.x * 4 + wv;           // 32*280 = 8960 waves
    const int sl   = w / TPS;
    const int rem  = w - sl * TPS;
    // edge tiles first (rem < NEDGE), interior after — tail shaping
    int trow, tcol;
    if (rem < 2 * TCOLS) {                      // top & bottom rows
        trow = (rem < TCOLS) ? 0 : (TROWS - 1);
        tcol = (rem < TCOLS) ? rem : rem - TCOLS;
    } else if (rem < NEDGE) {                   // left & right cols
        int e = rem - 2 * TCOLS;                // 0..75
        trow = 1 + (e % (TROWS - 2));
        tcol = (e < TROWS - 2) ? 0 : (TCOLS - 1);
    } else {                                    // interior: 38 rows x 5 cols
        int i2 = rem - NEDGE;
        trow = 1 + i2 / (TCOLS - 2);
        tcol = 1 + i2 % (TCOLS - 2);
    }
    const int gi0  = trow * TIR - HALO;
    const int gj   = tcol * TIC - 8 + lane;         // interior at lanes [8,56)
    const float* g = zs + (size_t)sl * HWc;

    float uf[TIR];
    if (rem >= NEDGE) tv_core<false>(g, gi0, gj, uf);   // wave-uniform branch
    else              tv_core<true >(g, gi0, gj, uf);

    // ---- 3-level Haar + soft-threshold (replicated-lane forward) ----
    const float sc1 = (lane & 1) ? -1.f : 1.f;
    const float sc2 = (lane & 2) ? -1.f : 1.f;
    const float sc3 = (lane & 4) ? -1.f : 1.f;

    float ll1[4], lh1[4], hl1[4], hh1[4];
#pragma unroll
    for (int k = 0; k < 4; k++) {
        float a0 = uf[2 * k], a1 = uf[2 * k + 1];
        float n0 = __shfl_xor(a0, 1), n1 = __shfl_xor(a1, 1);
        float h0 = a0 + n0, d0 = sc1 * (a0 - n0);   // replicated in both lanes
        float h1 = a1 + n1, d1 = sc1 * (a1 - n1);
        ll1[k] = (h0 + h1) * 0.5f;
        lh1[k] = softt((h0 - h1) * 0.5f);
        hl1[k] = softt((d0 + d1) * 0.5f);
        hh1[k] = softt((d0 - d1) * 0.5f);
    }
    float ll2[2], lh2[2], hl2[2], hh2[2];
#pragma unroll
    for (int k = 0; k < 2; k++) {
        float a0 = ll1[2 * k], a1 = ll1[2 * k + 1];
        float n0 = __shfl_xor(a0, 2), n1 = __shfl_xor(a1, 2);
        float h0 = a0 + n0, d0 = sc2 * (a0 - n0);
        float h1 = a1 + n1, d1 = sc2 * (a1 - n1);
        ll2[k] = (h0 + h1) * 0.5f;
        lh2[k] = softt((h0 - h1) * 0.5f);
        hl2[k] = softt((d0 + d1) * 0.5f);
        hh2[k] = softt((d0 - d1) * 0.5f);
    }
    float ll3, lh3, hl3, hh3;
    {
        float a0 = ll2[0], a1 = ll2[1];
        float n0 = __shfl_xor(a0, 4), n1 = __shfl_xor(a1, 4);
        float h0 = a0 + n0, d0 = sc3 * (a0 - n0);
        float h1 = a1 + n1, d1 = sc3 * (a1 - n1);
        ll3 = (h0 + h1) * 0.5f;
        lh3 = softt((h0 - h1) * 0.5f);
        hl3 = softt((d0 + d1) * 0.5f);
        hh3 = softt((d0 - d1) * 0.5f);
    }
    // ---- inverse (shuffle-free: values replicated within blocks) ----
    float l2p[2];
    l2p[0] = 0.5f * ((ll3 + lh3) + sc3 * (hl3 + hh3));
    l2p[1] = 0.5f * ((ll3 - lh3) + sc3 * (hl3 - hh3));
    float l1p[4];
#pragma unroll
    for (int k = 0; k < 2; k++) {
        l1p[2 * k]     = 0.5f * ((l2p[k] + lh2[k]) + sc2 * (hl2[k] + hh2[k]));
        l1p[2 * k + 1] = 0.5f * ((l2p[k] - lh2[k]) + sc2 * (hl2[k] - hh2[k]));
    }
    float xn[TIR];
#pragma unroll
    for (int k = 0; k < 4; k++) {
        xn[2 * k]     = 0.5f * ((l1p[k] + lh1[k]) + sc1 * (hl1[k] + hh1[k]));
        xn[2 * k + 1] = 0.5f * ((l1p[k] - lh1[k]) + sc1 * (hl1[k] - hh1[k]));
    }

    // ---- FISTA: z = xn + beta*(xn - x_old); x = xn ----
    const bool wcol = (lane >= 8) && (lane < 56) && ((unsigned)gj < (unsigned)WID);
    float* px = x + (size_t)sl * HWc;
    float* pz = z + (size_t)sl * HWc;
    const int gi_int0 = trow * TIR;
#pragma unroll
    for (int i = 0; i < TIR; i++) {
        int off = (gi_int0 + i) * WID + gj;
        if (STOREZ) {
            float xo = wcol ? px[off] : 0.f;
            float zn = xn[i] + beta * (xn[i] - xo);
            if (wcol) {
                px[off] = xn[i];
                pz[off] = zn;
            }
        } else {
            if (wcol) px[off] = xn[i];   // last iteration: only x needed
        }
    }
}

// ---------------- host orchestration ----------------
extern "C" void kernel_launch(void* const* d_in, const int* in_sizes, int n_in,
                              void* d_out, int out_size, void* d_ws, size_t ws_size,
                              hipStream_t stream) {
    const float* y    = (const float*)d_in[0];
    const float* mask = (const float*)d_in[1];
    float* x = (float*)d_out;

    float* ws = (float*)d_ws;
    float* z  = ws;                       // NTOT
    float* t1 = ws + (size_t)NTOT;        // NTOT
    float* t2 = ws + 2 * (size_t)NTOT;    // NTOT
    float* tw = ws + 3 * (size_t)NTOT;    // 2*14*64 floats twiddle tables
    float* twF = tw;                      // forward (SGN=-1)
    float* twI = tw + 14 * 64;            // inverse (SGN=+1)

    const int ROW_BLKS = (NIMG * 320) / 4;      // 1280 (1 line/wave)
    const int COL_BLKS = NIMG * (WID / CB);     // 640 (8 cols, 8 waves/block)
    const int TV_BLKS  = (NSL * TPS) / 4;       // 2240

    build_tw<<<1, 64, 0, stream>>>(tw);

    // x0 = ifft2c(y): col-inverse then row-inverse (dual store -> x and z)
    fft_col<0><<<COL_BLKS, 512, 0, stream>>>(y, t1, nullptr, nullptr, twF);
    fft_row<1, 3><<<ROW_BLKS, 256, 0, stream>>>(t1, x, nullptr, z, twI);

    float t = 1.f;
    for (int it = 0; it < 15; it++) {
        // row-forward; fused (col-forward + DC + col-inverse); row-inverse
        // with residual epilogue: zs = z - g
        fft_row<-1, 0><<<ROW_BLKS, 256, 0, stream>>>(z, t1, nullptr, nullptr, twF);
        fft_col<1><<<COL_BLKS, 512, 0, stream>>>(t1, t2, y, mask, twF);
        fft_row<1, 2><<<ROW_BLKS, 256, 0, stream>>>(t2, t1, z, nullptr, twI);

        // TV prox + wavelet shrinkage + FISTA momentum, one kernel
        float tn   = (1.f + sqrtf(1.f + 4.f * t * t)) * 0.5f;
        float beta = (t - 1.f) / tn;
        t = tn;
        if (it < 14)
            tv_wav_fista<true ><<<TV_BLKS, 256, 0, stream>>>(t1, x, z, beta);
        else
            tv_wav_fista<false><<<TV_BLKS, 256, 0, stream>>>(t1, x, z, beta);
    }
    (void)in_sizes; (void)n_in; (void)out_size; (void)ws_size;
}